// Round 5
// baseline (186.504 us; speedup 1.0000x reference)
//
#include <hip/hip_runtime.h>

// B=8, L=512, K=512, D=M=N=P=64, all fp32.
// ws: vkc = 8*512*64 floats (1 MB) | tmp = 8*512*64 floats (1 MB)

// ---------------------------------------------------------------------------
// K1 (proven): vkc[b,k,n] = sum_p vk[b,k,p,n] * vexp[b,k,p]
// ---------------------------------------------------------------------------
__global__ __launch_bounds__(256) void vkc_kernel(const float* __restrict__ vk,
                                                  const float* __restrict__ vexp,
                                                  float* __restrict__ vkc) {
    const int wave = (blockIdx.x << 2) + (threadIdx.x >> 6);  // b*512 + k
    const int lane = threadIdx.x & 63;

    const float ve_reg = vexp[wave * 64 + lane];
    const int n0 = (lane & 15) << 2;
    const float* base = vk + (long)wave * 4096;

    float ax = 0.f, ay = 0.f, az = 0.f, aw = 0.f;
    #pragma unroll
    for (int it = 0; it < 16; ++it) {
        const int p = (lane >> 4) + (it << 2);
        const float4 v4 = *(const float4*)(base + p * 64 + n0);
        const float w = __shfl(ve_reg, p, 64);
        ax += v4.x * w; ay += v4.y * w; az += v4.z * w; aw += v4.w * w;
    }
    ax += __shfl_down(ax, 32, 64); ax += __shfl_down(ax, 16, 64);
    ay += __shfl_down(ay, 32, 64); ay += __shfl_down(ay, 16, 64);
    az += __shfl_down(az, 32, 64); az += __shfl_down(az, 16, 64);
    aw += __shfl_down(aw, 32, 64); aw += __shfl_down(aw, 16, 64);

    if ((lane & 48) == 0) {
        float4 r; r.x = ax; r.y = ay; r.z = az; r.w = aw;
        *(float4*)(vkc + wave * 64 + n0) = r;
    }
}

// ---------------------------------------------------------------------------
// K2: per (batch, 8 l-rows), 512 threads: scores -> softmax -> tmp (global)
// ---------------------------------------------------------------------------
__global__ __launch_bounds__(512) void score_tmp_kernel(const float* __restrict__ q,
                                                        const float* __restrict__ k,
                                                        const float* __restrict__ vkc,
                                                        const float* __restrict__ scale_p,
                                                        float* __restrict__ tmp_g) {
    __shared__ float q_s[8 * 64];         // 2 KB
    __shared__ float sc[8][512];          // 16 KB
    __shared__ float tp[8][8][64];        // 16 KB

    const int t = threadIdx.x;
    const int wv = t >> 6;
    const int lane = t & 63;
    const int batch = blockIdx.x >> 6;
    const int l0 = (blockIdx.x & 63) << 3;

    const float scale = scale_p[0];

    // ---- phase 0: stage 8 q rows ----
    q_s[t] = q[(batch * 512 + l0) * 64 + t];
    __syncthreads();

    // ---- phase 1: thread t owns k-row t; 8 l-dots ----
    {
        const float4* krow = (const float4*)(k + (batch * 512 + t) * 64);
        const float4* q4 = (const float4*)q_s;
        float acc[8] = {0.f, 0.f, 0.f, 0.f, 0.f, 0.f, 0.f, 0.f};
        #pragma unroll
        for (int dc = 0; dc < 16; ++dc) {
            const float4 kv = krow[dc];
            #pragma unroll
            for (int l = 0; l < 8; ++l) {
                const float4 p = q4[l * 16 + dc];
                acc[l] += p.x * kv.x + p.y * kv.y + p.z * kv.z + p.w * kv.w;
            }
        }
        #pragma unroll
        for (int l = 0; l < 8; ++l) sc[l][t] = scale * acc[l];
    }
    __syncthreads();

    // ---- phase 2: softmax over K=512; wave wv -> l=wv ----
    {
        float v[8]; float mx = -1e30f;
        #pragma unroll
        for (int j = 0; j < 8; ++j) { v[j] = sc[wv][lane + 64 * j]; mx = fmaxf(mx, v[j]); }
        #pragma unroll
        for (int off = 32; off; off >>= 1) mx = fmaxf(mx, __shfl_xor(mx, off, 64));
        float s = 0.f;
        #pragma unroll
        for (int j = 0; j < 8; ++j) { v[j] = __expf(v[j] - mx); s += v[j]; }
        #pragma unroll
        for (int off = 32; off; off >>= 1) s += __shfl_xor(s, off, 64);
        const float inv = 1.0f / s;
        #pragma unroll
        for (int j = 0; j < 8; ++j) sc[wv][lane + 64 * j] = v[j] * inv;
    }
    __syncthreads();

    // ---- phase 3: tmp[l][n] = sum_k w[l][k]*vkc[b][k][n]; wave covers 64 k --
    {
        const float* vkcb = vkc + batch * 512 * 64;
        const int ksub = lane >> 4;
        const int n0 = (lane & 15) << 2;
        const int kbeg = wv << 6;
        float4 a[8];
        #pragma unroll
        for (int l = 0; l < 8; ++l) { a[l].x = 0.f; a[l].y = 0.f; a[l].z = 0.f; a[l].w = 0.f; }
        #pragma unroll
        for (int i = 0; i < 16; ++i) {
            const int kk = kbeg + (i << 2) + ksub;
            const float4 v4 = *(const float4*)(vkcb + kk * 64 + n0);
            #pragma unroll
            for (int l = 0; l < 8; ++l) {
                const float w = sc[l][kk];
                a[l].x += w * v4.x; a[l].y += w * v4.y;
                a[l].z += w * v4.z; a[l].w += w * v4.w;
            }
        }
        #pragma unroll
        for (int l = 0; l < 8; ++l) {
            a[l].x += __shfl_down(a[l].x, 32, 64); a[l].x += __shfl_down(a[l].x, 16, 64);
            a[l].y += __shfl_down(a[l].y, 32, 64); a[l].y += __shfl_down(a[l].y, 16, 64);
            a[l].z += __shfl_down(a[l].z, 32, 64); a[l].z += __shfl_down(a[l].z, 16, 64);
            a[l].w += __shfl_down(a[l].w, 32, 64); a[l].w += __shfl_down(a[l].w, 16, 64);
        }
        if (lane < 16) {
            #pragma unroll
            for (int l = 0; l < 8; ++l)
                *(float4*)&tp[wv][l][lane << 2] = a[l];
        }
    }
    __syncthreads();
    {   // reduce the 8 wave partials and write tmp to global (coalesced)
        float s = tp[0][wv][lane];
        #pragma unroll
        for (int w = 1; w < 8; ++w) s += tp[w][wv][lane];
        tmp_g[(batch * 512 + l0) * 64 + t] = s;
    }
}

// ---------------------------------------------------------------------------
// K3: one wave per (b,l) row: attn = vq.tmp -> residual + LN -> out.
// Zero block barriers; 16 hoisted 1 KB coalesced loads per wave.
// ---------------------------------------------------------------------------
__global__ __launch_bounds__(256) void out_kernel(const float* __restrict__ q,
                                                  const float* __restrict__ vq,
                                                  const float* __restrict__ tmp_g,
                                                  const float* __restrict__ gamma,
                                                  const float* __restrict__ beta,
                                                  float* __restrict__ out) {
    __shared__ float attn_s[4][64];

    const int wv = threadIdx.x >> 6;
    const int lane = threadIdx.x & 63;
    const int row = (blockIdx.x << 2) + wv;        // b*512 + l

    const float* vql = vq + (long)row * 4096;

    // hoist all 16 streaming loads (64 VGPRs) -> 16 outstanding 1 KB wave-loads
    float4 v[16];
    #pragma unroll
    for (int it = 0; it < 16; ++it)
        v[it] = *(const float4*)(vql + it * 256 + lane * 4);

    const float qv = q[row * 64 + lane];
    const int n0 = (lane & 15) << 2;
    const float4 t4 = *(const float4*)(tmp_g + row * 64 + n0);

    #pragma unroll
    for (int it = 0; it < 16; ++it) {
        float part = v[it].x * t4.x + v[it].y * t4.y + v[it].z * t4.z + v[it].w * t4.w;
        part += __shfl_down(part, 8, 16);
        part += __shfl_down(part, 4, 16);
        part += __shfl_down(part, 2, 16);
        part += __shfl_down(part, 1, 16);
        if ((lane & 15) == 0) attn_s[wv][it * 4 + (lane >> 4)] = part;
    }
    // attn_s[wv] produced+consumed by the same wave -> no block barrier

    const float x = qv + attn_s[wv][lane];
    float s1 = x, s2 = x * x;
    #pragma unroll
    for (int off = 32; off; off >>= 1) {
        s1 += __shfl_xor(s1, off, 64);
        s2 += __shfl_xor(s2, off, 64);
    }
    const float mean = s1 * (1.0f / 64.0f);
    const float var = s2 * (1.0f / 64.0f) - mean * mean;
    const float r = rsqrtf(var + 1e-3f);
    out[row * 64 + lane] = (x - mean) * r * gamma[lane] + beta[lane];
}

extern "C" void kernel_launch(void* const* d_in, const int* in_sizes, int n_in,
                              void* d_out, int out_size, void* d_ws, size_t ws_size,
                              hipStream_t stream) {
    const float* q     = (const float*)d_in[0];
    const float* k     = (const float*)d_in[1];
    const float* vq    = (const float*)d_in[2];
    const float* vk    = (const float*)d_in[3];
    const float* vexp  = (const float*)d_in[4];
    const float* scale = (const float*)d_in[5];
    const float* gamma = (const float*)d_in[6];
    const float* beta  = (const float*)d_in[7];
    float* out = (float*)d_out;

    float* vkc = (float*)d_ws;                 // 1 MB
    float* tmp = vkc + 8 * 512 * 64;           // 1 MB

    vkc_kernel<<<1024, 256, 0, stream>>>(vk, vexp, vkc);
    score_tmp_kernel<<<512, 512, 0, stream>>>(q, k, vkc, scale, tmp);
    out_kernel<<<1024, 256, 0, stream>>>(q, vq, tmp, gamma, beta, out);
}